// Round 6
// baseline (192.232 us; speedup 1.0000x reference)
//
#include <hip/hip_runtime.h>
#include <math.h>

typedef __attribute__((ext_vector_type(8))) short s8v;   // 8 x bf16 (4 VGPRs) — MFMA A/B frag
typedef __attribute__((ext_vector_type(4))) float f4v;   // 4 x fp32 — MFMA C/D frag
typedef unsigned short u16;
typedef unsigned int u32;

constexpr int Bsz = 4, NQ = 4096, NC = 1024, NH = 8, DH = 64, DI = 512, DC = 768;

__device__ __forceinline__ u16 f2bf(float f) {
  union { float f; u32 u; } v; v.f = f;
  u32 r = v.u + 0x7fff + ((v.u >> 16) & 1);  // RNE
  return (u16)(r >> 16);
}

// pack two f32 -> two bf16 in one dword (round-half-up) — used in V epilogue
__device__ __forceinline__ u32 pack2(float a, float b) {
  union { float f; u32 u; } ua, ub; ua.f = a; ub.f = b;
#if __has_builtin(__builtin_amdgcn_perm)
  return __builtin_amdgcn_perm(ub.u + 0x8000u, ua.u + 0x8000u, 0x07060302u);
#else
  return ((ub.u + 0x8000u) & 0xffff0000u) | ((ua.u + 0x8000u) >> 16);
#endif
}

// single-instruction RNE pack (v_cvt_pk_bf16_f32): lo16=bf16(a), hi16=bf16(b)
__device__ __forceinline__ u32 cvtpk(float a, float b) {
  u32 r;
  asm("v_cvt_pk_bf16_f32 %0, %1, %2" : "=v"(r) : "v"(a), "v"(b));
  return r;
}

#if __has_builtin(__builtin_amdgcn_exp2f)
#define EXP2(x) __builtin_amdgcn_exp2f(x)
#else
#define EXP2(x) exp2f(x)
#endif

// async global->LDS, 16B per lane (m97 pattern)
__device__ __forceinline__ void g2l16(const void* g, void* l) {
  __builtin_amdgcn_global_load_lds((const __attribute__((address_space(1))) u32*)g,
                                   (__attribute__((address_space(3))) u32*)l, 16, 0, 0);
}

// ---------------- prep: weight transposes only ----------------
__global__ __launch_bounds__(256) void prep(const float* __restrict__ Wq, const float* __restrict__ Wk,
                                            const float* __restrict__ Wv, const float* __restrict__ Wo,
                                            u16* __restrict__ wqT, u16* __restrict__ wkvT,
                                            u16* __restrict__ woT) {
  int idx = blockIdx.x;                   // [0,384)
  int z = idx / 96, rem = idx % 96, kx = rem % 12, ny = rem / 12;
  const float* src; u16* dst; int K; const int N = 512;
  if (z == 0)      { src = Wq; dst = wqT;              K = 512; }
  else if (z == 1) { src = Wk; dst = wkvT;             K = 768; }
  else if (z == 2) { src = Wv; dst = wkvT + 512 * 768; K = 768; }
  else             { src = Wo; dst = woT;              K = 512; }
  int k0 = kx * 64, n0 = ny * 64;
  if (k0 >= K) return;
  __shared__ u16 t[64][65];
  int tid = threadIdx.x, jr = tid & 63, ir = tid >> 6;
  for (int it = 0; it < 16; ++it) { int i = it * 4 + ir; t[i][jr] = f2bf(src[(size_t)(k0 + i) * N + n0 + jr]); }
  __syncthreads();
  for (int it = 0; it < 16; ++it) { int i = it * 4 + ir; dst[(size_t)(n0 + i) * K + k0 + jr] = t[jr][i]; }
}

// ---------------- shared GEMM body: 64x128 tile, BK=32, high-TLP ----------------
// R6: R1-R5 showed structure-invariance (~45-58 µs across 2buf/counted/dual-N) —
// the limiter is latency exposure at low wave count, not pipeline shape or traffic.
// Fix: small tile (BM=64) -> acc 8 f4v, LDS 24KB, lb(256,4): 4 INDEPENDENT blocks/CU
// (16 waves resident vs 12), grids 1536/1024 (6/4 queued per CU smooths tails).
// Busy/latency arithmetic: ~300 cy busy per block-iter vs ~900 cy load latency ->
// 4 independent barrier groups cover it. Simple R2-style 2-buf __syncthreads loop
// (counted-vmcnt proven neutral). XOR-chunk swizzle (conflict-free, R2/R4-verified).
// F32A: A fp32 in global; reg-stage 2xfloat4 -> cvt_pk -> ds_write (one reg set).
// Waves: wm=(wave>>1)*32, wn=(wave&1)*64. Al: [2][64][32]. Bl: [2][128][32].
template <int MODE, bool F32A>
__device__ __forceinline__ void gemm_body(const void* __restrict__ Av, const u16* __restrict__ Bt,
                                          void* __restrict__ C0, void* __restrict__ C1,
                                          const float* __restrict__ bias, int N, int K,
                                          float oscale, int nbx, int mby,
                                          u16* Al, u16* Bl) {
  int mb = mby * 64, nb = nbx * 128;
  int tid = threadIdx.x, lane = tid & 63, quad = lane >> 4, l16 = lane & 15, wave = tid >> 6;
  int wm = (wave >> 1) * 32, wn = (wave & 1) * 64;
  f4v acc[2][4];
  #pragma unroll
  for (int i = 0; i < 2; i++)
    #pragma unroll
    for (int j = 0; j < 4; j++) acc[i][j] = (f4v){0.f, 0.f, 0.f, 0.f};

  int r0 = tid >> 2;                               // [0,64)
  int cs = ((tid & 3) ^ ((r0 >> 1) & 3)) * 8;      // swizzled source chunk -> element offset
  int lin = tid * 8;                               // linear LDS dest (elements)
  const u16* Bp0 = Bt + (size_t)(nb + r0) * K + cs;    // B rows 0-63
  const u16* Bp1 = Bp0 + (size_t)64 * K;               // B rows 64-127
  const float* Af0 = nullptr;
  const u16* Ap0 = nullptr;
  if constexpr (F32A) Af0 = (const float*)Av + (size_t)(mb + r0) * K + cs;
  else                Ap0 = (const u16*)Av + (size_t)(mb + r0) * K + cs;
  float4 ra[2];                                    // one in-flight fp32 A set (literal idx only)

#define BSTG(k0, bl_) do { g2l16(Bp0 + (k0), (bl_) + lin); g2l16(Bp1 + (k0), (bl_) + lin + 2048); } while (0)
#define ASTG(k0, al_) do { g2l16(Ap0 + (k0), (al_) + lin); } while (0)
#define ALD(k0) do { ra[0] = *(const float4*)(Af0 + (k0)); ra[1] = *(const float4*)(Af0 + (k0) + 4); } while (0)
#define AWR(al_) do { union { u32 d[4]; s8v v; } ua; \
    ua.d[0] = cvtpk(ra[0].x, ra[0].y); ua.d[1] = cvtpk(ra[0].z, ra[0].w); \
    ua.d[2] = cvtpk(ra[1].x, ra[1].y); ua.d[3] = cvtpk(ra[1].z, ra[1].w); \
    *(s8v*)((al_) + lin) = ua.v; } while (0)

  if constexpr (F32A) { ALD(0); BSTG(0, Bl); AWR(Al); }
  else { ASTG(0, Al); BSTG(0, Bl); }

  int nk = K >> 5;
  int swq8 = (quad ^ ((l16 >> 1) & 3)) * 8;        // read-side chunk, loop-invariant
  for (int t = 0; t < nk; ++t) {
    __syncthreads();                               // drains staging (vmcnt+lgkm) + dbuf WAR
    int cur = t & 1, nxtb = cur ^ 1;
    if (t + 1 < nk) {
      int nxt = (t + 1) * 32;
      if constexpr (F32A) ALD(nxt); else ASTG(nxt, Al + nxtb * 2048);
      BSTG(nxt, Bl + nxtb * 4096);
    }
    const u16* ar = Al + cur * 2048;
    const u16* br = Bl + cur * 4096;
    s8v af[2], bfr[4];
    #pragma unroll
    for (int i = 0; i < 2; i++) af[i] = *(const s8v*)(ar + (wm + i * 16 + l16) * 32 + swq8);
    #pragma unroll
    for (int j = 0; j < 4; j++) bfr[j] = *(const s8v*)(br + (wn + j * 16 + l16) * 32 + swq8);
    #pragma unroll
    for (int i = 0; i < 2; i++)
      #pragma unroll
      for (int j = 0; j < 4; j++)
        acc[i][j] = __builtin_amdgcn_mfma_f32_16x16x32_bf16(af[i], bfr[j], acc[i][j], 0, 0, 0);
    if constexpr (F32A) {
      if (t + 1 < nk) AWR(Al + nxtb * 2048);       // lands after MFMA cluster; next sync orders it
    }
  }
#undef BSTG
#undef ASTG
#undef ALD
#undef AWR
  #pragma unroll
  for (int i = 0; i < 2; i++) {
    int rbase = mb + wm + i * 16 + quad * 4;
    #pragma unroll
    for (int j = 0; j < 4; j++) {
      int col = nb + wn + j * 16 + l16;
      if (MODE == 0) {
        u16* Cb = (u16*)C0;
        #pragma unroll
        for (int r = 0; r < 4; r++) Cb[(size_t)(rbase + r) * N + col] = f2bf(acc[i][j][r] * oscale);
      } else if (MODE == 1) {
        float* Cf = (float*)C0;
        #pragma unroll
        for (int r = 0; r < 4; r++) Cf[(size_t)(rbase + r) * N + col] = acc[i][j][r] + bias[col];
      } else {
        if (col < 512) {                  // K projection -> Kb [b*NC+t][512]
          u16* Kb = (u16*)C0;
          #pragma unroll
          for (int r = 0; r < 4; r++) Kb[(size_t)(rbase + r) * 512 + col] = f2bf(acc[i][j][r]);
        } else {                          // V projection -> Vt, transposed + key-permuted
          u16* Vt = (u16*)C1;
          int hd = col - 512, h = hd >> 6, d = hd & 63;
          int bb = rbase >> 10, tl = rbase & 1023;
          int tbase = tl & ~63, a0 = tl & 63;          // a0 = quad*4-aligned key-local idx
          int pb = (a0 & 32) + ((a0 & 15) >> 2) * 8 + (((a0 >> 4) & 1) << 2);
          uint2 ov;
          ov.x = pack2(acc[i][j][0], acc[i][j][1]);
          ov.y = pack2(acc[i][j][2], acc[i][j][3]);
          *(uint2*)(Vt + ((size_t)(bb * NH + h) * DH + d) * NC + tbase + pb) = ov;
        }
      }
    }
  }
}

// ---------------- fused QKV projection, fp32 A direct, XCD-chunked swizzle ----------------
// 1536 blocks (6/CU queued, 4 resident): per XCD 64 KV (24 K-steps, first) + 128 Q.
// Same-XCD blocks share A-panels (per-XCD slice ~= L2), R4-verified FETCH 116->31 MB.
__global__ __launch_bounds__(256, 4) void proj_all(const float* __restrict__ x, const float* __restrict__ ctx,
                                                   const u16* __restrict__ wqT, const u16* __restrict__ wkvT,
                                                   u16* __restrict__ Qb, u16* __restrict__ Kb,
                                                   u16* __restrict__ Vtb, float qscale) {
  __shared__ alignas(16) u16 Al[2][64][32];    // 8 KB
  __shared__ alignas(16) u16 Bl[2][128][32];   // 16 KB
  int bx = blockIdx.x;
  int xcd = bx & 7, off = bx >> 3;        // off in [0,192)
  if (off < 64) {  // KV: M=4096, N=1024, K=768; 512 blocks
    int bi = xcd * 64 + off;              // [0,512)
    gemm_body<2, true>(ctx, wkvT, Kb, Vtb, nullptr, 1024, 768, 1.0f, bi & 7, bi >> 3,
                       (u16*)Al, (u16*)Bl);
  } else {         // Q: M=16384, N=512, K=512; 1024 blocks
    int bi = xcd * 128 + (off - 64);      // [0,1024)
    gemm_body<0, true>(x, wqT, Qb, nullptr, nullptr, 512, 512, qscale, bi & 3, bi >> 2,
                       (u16*)Al, (u16*)Bl);
  }
}

// ---------------- output projection (fp32 out + bias), XCD-chunked swizzle ----------------
__global__ __launch_bounds__(256, 4) void outproj(const u16* __restrict__ Ob, const u16* __restrict__ woT,
                                                  float* __restrict__ out, const float* __restrict__ bo) {
  __shared__ alignas(16) u16 Al[2][64][32];
  __shared__ alignas(16) u16 Bl[2][128][32];
  int bx = blockIdx.x;
  int idx = (bx & 7) * 128 + (bx >> 3);   // [0,1024): same-XCD blocks share Ob panels
  gemm_body<1, false>(Ob, woT, out, nullptr, bo, 512, 512, 1.0f, idx & 3, idx >> 2,
                      (u16*)Al, (u16*)Bl);
}

// ---------------- flash cross-attention: 32 q/wave, 64-key tiles, 4 blocks/CU ----------------
// (unchanged from R1: MFMA-ones denominator, cvt_pk packs, pipelined chunks + setprio)
__global__ __launch_bounds__(256, 4) void attn(const u16* __restrict__ Q, const u16* __restrict__ Kb,
                                               const u16* __restrict__ Vt, u16* __restrict__ O) {
  __shared__ alignas(16) u16 Kl[2][64][64];   // 16 KB
  __shared__ alignas(16) u16 Vl[2][64][64];   // 16 KB
  int qt = blockIdx.x, h = blockIdx.y, b = blockIdx.z;
  int tid = threadIdx.x, wave = tid >> 6, lane = tid & 63, quad = lane >> 4, l16 = lane & 15;
  int q0 = qt * 128 + wave * 32;
  int x7 = l16 & 7;

  int kr = tid >> 3, kc = (tid & 7) ^ (kr & 7);
  const u16* kg = Kb + ((size_t)b * NC + kr) * 512 + h * DH + kc * 8;
  const u16* vg = Vt + ((size_t)(b * NH + h) * DH + kr) * NC + kc * 8;

#define ASTAGE(kt, buf) do { \
    const u16* kg_ = kg + (size_t)(kt) * 64 * 512; \
    const u16* vg_ = vg + (kt) * 64; \
    u16* kl_ = (u16*)Kl + (buf) * 4096; u16* vl_ = (u16*)Vl + (buf) * 4096; \
    g2l16(kg_,            kl_ + tid * 8); \
    g2l16(kg_ + 32 * 512, kl_ + (tid + 256) * 8); \
    g2l16(vg_,            vl_ + tid * 8); \
    g2l16(vg_ + 32 * NC,  vl_ + (tid + 256) * 8); } while (0)

  s8v aq[2][2];
  {
    const u16* Qp = Q + ((size_t)b * NQ + q0 + l16) * DI + h * DH + quad * 8;
    #pragma unroll
    for (int n = 0; n < 2; n++) {
      aq[n][0] = *(const s8v*)(Qp + (size_t)n * 16 * DI);
      aq[n][1] = *(const s8v*)(Qp + (size_t)n * 16 * DI + 32);
    }
  }
  s8v vones;
  #pragma unroll
  for (int i = 0; i < 8; i++) vones[i] = (short)0x3F80;

  f4v oacc[4][2];
  f4v lacc[2];
  #pragma unroll
  for (int d = 0; d < 4; d++)
    #pragma unroll
    for (int n = 0; n < 2; n++) oacc[d][n] = (f4v){0.f, 0.f, 0.f, 0.f};
  #pragma unroll
  for (int n = 0; n < 2; n++) lacc[n] = (f4v){0.f, 0.f, 0.f, 0.f};

  ASTAGE(0, 0);
  for (int kt = 0; kt < NC / 64; ++kt) {
    int buf = kt & 1;
    __syncthreads();
    if (kt + 1 < NC / 64) ASTAGE(kt + 1, buf ^ 1);
    const u16* kb = (const u16*)Kl + buf * 4096;
    const u16* vb = (const u16*)Vl + buf * 4096;

    f4v S0[2][2], S1[2][2];
    #pragma unroll
    for (int mi = 0; mi < 2; mi++)
      #pragma unroll
      for (int n = 0; n < 2; n++) { S0[mi][n] = (f4v){0.f,0.f,0.f,0.f}; S1[mi][n] = (f4v){0.f,0.f,0.f,0.f}; }
    __builtin_amdgcn_s_setprio(1);
    #pragma unroll
    for (int cd = 0; cd < 2; cd++) {
      int ch = ((4 * cd + quad) ^ x7) * 8;
      s8v k00 = *(const s8v*)(kb + (l16     ) * 64 + ch);
      s8v k01 = *(const s8v*)(kb + (l16 + 16) * 64 + ch);
      #pragma unroll
      for (int n = 0; n < 2; n++) {
        S0[0][n] = __builtin_amdgcn_mfma_f32_16x16x32_bf16(k00, aq[n][cd], S0[0][n], 0, 0, 0);
        S0[1][n] = __builtin_amdgcn_mfma_f32_16x16x32_bf16(k01, aq[n][cd], S0[1][n], 0, 0, 0);
      }
      s8v k10 = *(const s8v*)(kb + (l16 + 32) * 64 + ch);
      s8v k11 = *(const s8v*)(kb + (l16 + 48) * 64 + ch);
      #pragma unroll
      for (int n = 0; n < 2; n++) {
        S1[0][n] = __builtin_amdgcn_mfma_f32_16x16x32_bf16(k10, aq[n][cd], S1[0][n], 0, 0, 0);
        S1[1][n] = __builtin_amdgcn_mfma_f32_16x16x32_bf16(k11, aq[n][cd], S1[1][n], 0, 0, 0);
      }
    }
    __builtin_amdgcn_s_setprio(0);

    s8v pf0[2];
    #pragma unroll
    for (int n = 0; n < 2; n++) {
      float p00 = EXP2(S0[0][n][0]), p01 = EXP2(S0[0][n][1]), p02 = EXP2(S0[0][n][2]), p03 = EXP2(S0[0][n][3]);
      float p10 = EXP2(S0[1][n][0]), p11 = EXP2(S0[1][n][1]), p12 = EXP2(S0[1][n][2]), p13 = EXP2(S0[1][n][3]);
      union { u32 d[4]; s8v v; } u;
      u.d[0] = cvtpk(p00, p01); u.d[1] = cvtpk(p02, p03);
      u.d[2] = cvtpk(p10, p11); u.d[3] = cvtpk(p12, p13);
      pf0[n] = u.v;
    }
    __builtin_amdgcn_s_setprio(1);
    #pragma unroll
    for (int n = 0; n < 2; n++)
      lacc[n] = __builtin_amdgcn_mfma_f32_16x16x32_bf16(vones, pf0[n], lacc[n], 0, 0, 0);
    #pragma unroll
    for (int d = 0; d < 4; d++) {
      int ch = (quad ^ x7) * 8;
      s8v vf = *(const s8v*)(vb + (d * 16 + l16) * 64 + ch);
      #pragma unroll
      for (int n = 0; n < 2; n++)
        oacc[d][n] = __builtin_amdgcn_mfma_f32_16x16x32_bf16(vf, pf0[n], oacc[d][n], 0, 0, 0);
    }
    __builtin_amdgcn_s_setprio(0);

    s8v pf1[2];
    #pragma unroll
    for (int n = 0; n < 2; n++) {
      float p00 = EXP2(S1[0][n][0]), p01 = EXP2(S1[0][n][1]), p02 = EXP2(S1[0][n][2]), p03 = EXP2(S1[0][n][3]);
      float p10 = EXP2(S1[1][n][0]), p11 = EXP2(S1[1][n][1]), p12 = EXP2(S1[1][n][2]), p13 = EXP2(S1[1][n][3]);
      union { u32 d[4]; s8v v; } u;
      u.d[0] = cvtpk(p00, p01); u.d[1] = cvtpk(p02, p03);
      u.d[2] = cvtpk(p10, p11); u.d[3] = cvtpk(p12, p13);
      pf1[n] = u.v;
    }
    __builtin_amdgcn_s_setprio(1);
    #pragma unroll
    for (int n = 0; n < 2; n++)
      lacc[n] = __builtin_amdgcn_mfma_f32_16x16x32_bf16(vones, pf1[n], lacc[n], 0, 0, 0);
    #pragma unroll
    for (int d = 0; d < 4; d++) {
      int ch = ((4 + quad) ^ x7) * 8;
      s8v vf = *(const s8v*)(vb + (d * 16 + l16) * 64 + ch);
      #pragma unroll
      for (int n = 0; n < 2; n++)
        oacc[d][n] = __builtin_amdgcn_mfma_f32_16x16x32_bf16(vf, pf1[n], oacc[d][n], 0, 0, 0);
    }
    __builtin_amdgcn_s_setprio(0);
  }
#undef ASTAGE

  float inv[2];
  #pragma unroll
  for (int n = 0; n < 2; n++) inv[n] = 1.0f / lacc[n][0];

  #pragma unroll
  for (int d = 0; d < 4; d++)
    #pragma unroll
    for (int n = 0; n < 2; n++) {
      int q = q0 + n * 16 + l16;
      uint2 ov;
      ov.x = cvtpk(oacc[d][n][0] * inv[n], oacc[d][n][1] * inv[n]);
      ov.y = cvtpk(oacc[d][n][2] * inv[n], oacc[d][n][3] * inv[n]);
      *(uint2*)(O + ((size_t)b * NQ + q) * DI + h * DH + d * 16 + quad * 4) = ov;
    }
}

extern "C" void kernel_launch(void* const* d_in, const int* in_sizes, int n_in,
                              void* d_out, int out_size, void* d_ws, size_t ws_size,
                              hipStream_t stream) {
  const float* x   = (const float*)d_in[0];
  const float* ctx = (const float*)d_in[1];
  const float* Wq  = (const float*)d_in[2];
  const float* Wk  = (const float*)d_in[3];
  const float* Wv  = (const float*)d_in[4];
  const float* Wo  = (const float*)d_in[5];
  const float* bo  = (const float*)d_in[6];
  float* out = (float*)d_out;

  u16* w    = (u16*)d_ws;                // workspace layout (bf16 elems)
  u16* wqT  = w;                         // 262144
  u16* wkvT = wqT  + 262144;             // 786432 (Wk^T rows 0-511, Wv^T rows 512-1023)
  u16* woT  = wkvT + 786432;             // 262144
  u16* Qb   = woT  + 262144;             // 8388608 (pre-scaled by 0.125*log2e)
  u16* Kbuf = Qb   + 8388608;            // 2097152 ([b*1024+t][512])
  u16* Vtb  = Kbuf + 2097152;            // 2097152 (key-permuted V^T)
  u16* Ob   = Vtb  + 2097152;            // 8388608

  const float qscale = 0.125f * 1.44269504f;  // softmax scale + log2(e) folded into Q

  prep<<<384, 256, 0, stream>>>(Wq, Wk, Wv, Wo, wqT, wkvT, woT);
  proj_all<<<1536, 256, 0, stream>>>(x, ctx, wqT, wkvT, Qb, Kbuf, Vtb, qscale);
  attn<<<dim3(32, 8, 4), 256, 0, stream>>>(Qb, Kbuf, Vtb, Ob);
  outproj<<<1024, 256, 0, stream>>>(Ob, woT, out, bo);
}

// Round 7
// 179.150 us; speedup vs baseline: 1.0730x; 1.0730x over previous
//
#include <hip/hip_runtime.h>
#include <math.h>

typedef __attribute__((ext_vector_type(8))) short s8v;   // 8 x bf16 (4 VGPRs) — MFMA A/B frag
typedef __attribute__((ext_vector_type(4))) float f4v;   // 4 x fp32 — MFMA C/D frag
typedef unsigned short u16;
typedef unsigned int u32;

constexpr int Bsz = 4, NQ = 4096, NC = 1024, NH = 8, DH = 64, DI = 512, DC = 768;

__device__ __forceinline__ u16 f2bf(float f) {
  union { float f; u32 u; } v; v.f = f;
  u32 r = v.u + 0x7fff + ((v.u >> 16) & 1);  // RNE
  return (u16)(r >> 16);
}

__device__ __forceinline__ u32 pack2(float a, float b) {
  union { float f; u32 u; } ua, ub; ua.f = a; ub.f = b;
#if __has_builtin(__builtin_amdgcn_perm)
  return __builtin_amdgcn_perm(ub.u + 0x8000u, ua.u + 0x8000u, 0x07060302u);
#else
  return ((ub.u + 0x8000u) & 0xffff0000u) | ((ua.u + 0x8000u) >> 16);
#endif
}

// single-instruction RNE pack (v_cvt_pk_bf16_f32)
__device__ __forceinline__ u32 cvtpk(float a, float b) {
  u32 r;
  asm("v_cvt_pk_bf16_f32 %0, %1, %2" : "=v"(r) : "v"(a), "v"(b));
  return r;
}

#if __has_builtin(__builtin_amdgcn_exp2f)
#define EXP2(x) __builtin_amdgcn_exp2f(x)
#else
#define EXP2(x) exp2f(x)
#endif

// async global->LDS, 16B per lane (m97 pattern)
__device__ __forceinline__ void g2l16(const void* g, void* l) {
  __builtin_amdgcn_global_load_lds((const __attribute__((address_space(1))) u32*)g,
                                   (__attribute__((address_space(3))) u32*)l, 16, 0, 0);
}

// ---------------- prep: casts + all weight transposes in one launch (R0-verified) --------
__global__ __launch_bounds__(256) void prep(const float* __restrict__ x, const float* __restrict__ ctx,
                                            const float* __restrict__ Wq, const float* __restrict__ Wk,
                                            const float* __restrict__ Wv, const float* __restrict__ Wo,
                                            u16* __restrict__ xb, u16* __restrict__ cb,
                                            u16* __restrict__ wqT, u16* __restrict__ wkvT,
                                            u16* __restrict__ woT) {
  int bx = blockIdx.x;
  if (bx < 11264) {                       // cast path: x then ctx, float4-vectorized
    const int NX4 = Bsz * NQ * DI / 4;    // 2097152
    const int NC4 = Bsz * NC * DC / 4;    // 786432
    int i = bx * 256 + threadIdx.x;
    float4 v; u16* dst; int j;
    if (i < NX4) { v = ((const float4*)x)[i]; dst = xb; j = i; }
    else { j = i - NX4; if (j >= NC4) return; v = ((const float4*)ctx)[j]; dst = cb; }
    ushort4 o; o.x = f2bf(v.x); o.y = f2bf(v.y); o.z = f2bf(v.z); o.w = f2bf(v.w);
    ((ushort4*)dst)[j] = o;
    return;
  }
  int idx = bx - 11264;                   // [0,384): weight transpose W[K][N] -> W^T[N][K] bf16
  int z = idx / 96, rem = idx % 96, kx = rem % 12, ny = rem / 12;
  const float* src; u16* dst; int K; const int N = 512;
  if (z == 0)      { src = Wq; dst = wqT;              K = 512; }
  else if (z == 1) { src = Wk; dst = wkvT;             K = 768; }
  else if (z == 2) { src = Wv; dst = wkvT + 512 * 768; K = 768; }
  else             { src = Wo; dst = woT;              K = 512; }
  int k0 = kx * 64, n0 = ny * 64;
  if (k0 >= K) return;
  __shared__ u16 t[64][65];
  int tid = threadIdx.x, jr = tid & 63, ir = tid >> 6;
  for (int it = 0; it < 16; ++it) { int i = it * 4 + ir; t[i][jr] = f2bf(src[(size_t)(k0 + i) * N + n0 + jr]); }
  __syncthreads();
  for (int it = 0; it < 16; ++it) { int i = it * 4 + ir; dst[(size_t)(n0 + i) * K + k0 + jr] = t[jr][i]; }
}

// ---------------- 8-phase GEMM body: 128x256 tile, BK=64, 512 threads, 8 waves ----------------
// R7: the T3+T4 8-phase counted-vmcnt schedule (m196->m198 +28-41%; 2-phase structure was
// invariant across R2-R6 probes, pinned at ~47us by the stage+vmcnt+barrier critical path).
// 3 K-tile LDS buffers (48KB each, 144KB total): iteration computes tiles t,t+1; phases 1-3
// stage tile t+2 (2 g2l16/thread per phase) into the buffer freed LAST iteration; phases 5-7
// stage t+3 into tile t's buffer (reads complete at the phase-4 post-barrier). vmcnt(6) at
// phases 4 and 8 only (6 staging instrs/wave per tile; 1 tile left in flight after wait);
// a following s_barrier publishes across waves. Never vmcnt(0) except the final iteration.
// LDS tiles [rows][64] bf16 with 3-bit XOR chunk swizzle (chunk ^= row&7; G4's D=128B fix):
// linear g2l16 dest + pre-swizzled global source + swizzled read (both-sides involution).
// Per phase: 2(+4) ds_read_b128, 8 MFMA wrapped in setprio(1/0) (T5: +21-39% on 8-phase).
template <int MODE>
__device__ __forceinline__ void gemm8p(const u16* __restrict__ A, const u16* __restrict__ Bt,
                                       void* __restrict__ C0, void* __restrict__ C1,
                                       const float* __restrict__ bias, int N, int K,
                                       float oscale, int nbx, int mby,
                                       u16* Ash, u16* Bsh) {   // Ash: 3*8192, Bsh: 3*16384 (u16)
  int tid = threadIdx.x;                  // 0..511
  int lane = tid & 63, quad = lane >> 4, l16 = lane & 15, wave = tid >> 6;
  int wm = (wave >> 2) * 64, wn = (wave & 3) * 64;   // 2M x 4N wave grid; 64x64 per wave
  int mb = mby * 128, nb = nbx * 256;
  int x7 = l16 & 7;
  f4v acc[4][4];
  #pragma unroll
  for (int i = 0; i < 4; i++)
    #pragma unroll
    for (int j = 0; j < 4; j++) acc[i][j] = (f4v){0.f, 0.f, 0.f, 0.f};

  // staging addresses: thread t -> row t>>3 (of a 64-row unit), source chunk (t&7)^(row&7)
  int srow = tid >> 3;
  int sc = ((tid & 7) ^ (srow & 7)) * 8;
  const u16* Ap0 = A  + (size_t)(mb + srow) * K + sc;   // A rows 0-63 ; +64*K -> rows 64-127
  const u16* Bq0 = Bt + (size_t)(nb + srow) * K + sc;   // B rows 0-63 ; +u*64*K -> unit u
  int lin = tid * 8;                                    // linear LDS dest (elements)

#define SA(ts, dst) do { const u16* s_ = Ap0 + (size_t)(ts) * 64; \
    g2l16(s_, (dst) + lin); g2l16(s_ + (size_t)64 * K, (dst) + 4096 + lin); } while (0)
#define SB0(ts, dst) do { const u16* s_ = Bq0 + (size_t)(ts) * 64; \
    g2l16(s_, (dst) + lin); g2l16(s_ + (size_t)64 * K, (dst) + 4096 + lin); } while (0)
#define SB1(ts, dst) do { const u16* s_ = Bq0 + (size_t)(ts) * 64 + (size_t)128 * K; \
    g2l16(s_, (dst) + 8192 + lin); g2l16(s_ + (size_t)64 * K, (dst) + 12288 + lin); } while (0)

  // read-side swizzled chunk offsets (elements), per kk slab
  int ak0 = ((0 + quad) ^ x7) * 8;
  int ak1 = ((4 + quad) ^ x7) * 8;

  s8v bfr[4];
  // PHASE: ds-reads -> stage issue -> [vmcnt] -> barrier -> setprio MFMA -> barrier.
  // WAITN: 6 = counted wait, 0 = drain, -1 = none (runtime-selected).
#define PHASE(ABUF, BBUF, AKK, IP, LOADB, WAITN, ...) do { \
    if (LOADB) { \
      bfr[0] = *(const s8v*)((BBUF) + (wn +  0 + l16) * 64 + (AKK)); \
      bfr[1] = *(const s8v*)((BBUF) + (wn + 16 + l16) * 64 + (AKK)); \
      bfr[2] = *(const s8v*)((BBUF) + (wn + 32 + l16) * 64 + (AKK)); \
      bfr[3] = *(const s8v*)((BBUF) + (wn + 48 + l16) * 64 + (AKK)); \
    } \
    s8v af0 = *(const s8v*)((ABUF) + (wm + (IP) * 32 + l16) * 64 + (AKK)); \
    s8v af1 = *(const s8v*)((ABUF) + (wm + (IP) * 32 + 16 + l16) * 64 + (AKK)); \
    __VA_ARGS__; \
    { int wv_ = (WAITN); \
      if (wv_ == 6) asm volatile("s_waitcnt vmcnt(6)" ::: "memory"); \
      else if (wv_ == 0) asm volatile("s_waitcnt vmcnt(0)" ::: "memory"); } \
    asm volatile("" ::: "memory"); __builtin_amdgcn_s_barrier(); asm volatile("" ::: "memory"); \
    __builtin_amdgcn_s_setprio(1); \
    _Pragma("unroll") \
    for (int j = 0; j < 4; j++) { \
      acc[(IP)*2][j]   = __builtin_amdgcn_mfma_f32_16x16x32_bf16(af0, bfr[j], acc[(IP)*2][j],   0, 0, 0); \
      acc[(IP)*2+1][j] = __builtin_amdgcn_mfma_f32_16x16x32_bf16(af1, bfr[j], acc[(IP)*2+1][j], 0, 0, 0); \
    } \
    __builtin_amdgcn_s_setprio(0); \
    asm volatile("" ::: "memory"); __builtin_amdgcn_s_barrier(); asm volatile("" ::: "memory"); \
  } while (0)

  u16 *A0 = Ash, *A1 = Ash + 8192, *A2 = Ash + 16384;
  u16 *B0 = Bsh, *B1 = Bsh + 16384, *B2 = Bsh + 32768;

  // prologue: stage tiles 0 and 1 (6 staging instrs each); wait tile 0 landed, keep 1 in flight
  SA(0, A0); SB0(0, B0); SB1(0, B0);
  SA(1, A1); SB0(1, B1); SB1(1, B1);
  asm volatile("s_waitcnt vmcnt(6)" ::: "memory");
  __builtin_amdgcn_s_barrier();
  asm volatile("" ::: "memory");

  int nkt = K >> 6;                        // K-tiles of 64 (8 or 12 here; always even)
  for (int t2 = 0; t2 < nkt; t2 += 2) {
    bool more = (t2 + 2 < nkt);
    // ---- K-tile t2 from A0/B0; stage t2+2 -> A2/B2 ----
    PHASE(A0, B0, ak0, 0, true,  -1, if (more) SA(t2 + 2, A2));
    PHASE(A0, B0, ak0, 1, false, -1, if (more) SB0(t2 + 2, B2));
    PHASE(A0, B0, ak1, 0, true,  -1, if (more) SB1(t2 + 2, B2));
    PHASE(A0, B0, ak1, 1, false, (more ? 6 : 0), );
    // ---- K-tile t2+1 from A1/B1; stage t2+3 -> A0/B0 (freed at phase-4 barrier) ----
    PHASE(A1, B1, ak0, 0, true,  -1, if (more) SA(t2 + 3, A0));
    PHASE(A1, B1, ak0, 1, false, -1, if (more) SB0(t2 + 3, B0));
    PHASE(A1, B1, ak1, 0, true,  -1, if (more) SB1(t2 + 3, B0));
    PHASE(A1, B1, ak1, 1, false, (more ? 6 : -1), );
    // rotate: next (cur0, cur1, spare) = (old spare, old cur0, old cur1)
    u16* tA = A0; A0 = A2; A2 = A1; A1 = tA;
    u16* tB = B0; B0 = B2; B2 = B1; B1 = tB;
  }
#undef PHASE
#undef SA
#undef SB0
#undef SB1

  // ---------------- epilogue (same mapping as verified 4x4 epilogues) ----------------
  #pragma unroll
  for (int i = 0; i < 4; i++) {
    int rbase = mb + wm + i * 16 + quad * 4;
    #pragma unroll
    for (int j = 0; j < 4; j++) {
      int col = nb + wn + j * 16 + l16;
      if (MODE == 0) {
        u16* Cb = (u16*)C0;
        #pragma unroll
        for (int r = 0; r < 4; r++) Cb[(size_t)(rbase + r) * N + col] = f2bf(acc[i][j][r] * oscale);
      } else if (MODE == 1) {
        float* Cf = (float*)C0;
        #pragma unroll
        for (int r = 0; r < 4; r++) Cf[(size_t)(rbase + r) * N + col] = acc[i][j][r] + bias[col];
      } else {
        if (col < 512) {                  // K projection -> Kb [b*NC+t][512]
          u16* Kb = (u16*)C0;
          #pragma unroll
          for (int r = 0; r < 4; r++) Kb[(size_t)(rbase + r) * 512 + col] = f2bf(acc[i][j][r]);
        } else {                          // V projection -> Vt, transposed + key-permuted
          u16* Vt = (u16*)C1;
          int hd = col - 512, h = hd >> 6, d = hd & 63;
          int bb = rbase >> 10, tl = rbase & 1023;
          int tbase = tl & ~63, a0 = tl & 63;
          int pb = (a0 & 32) + ((a0 & 15) >> 2) * 8 + (((a0 >> 4) & 1) << 2);
          uint2 ov;
          ov.x = pack2(acc[i][j][0], acc[i][j][1]);
          ov.y = pack2(acc[i][j][2], acc[i][j][3]);
          *(uint2*)(Vt + ((size_t)(bb * NH + h) * DH + d) * NC + tbase + pb) = ov;
        }
      }
    }
  }
}

// ---------------- fused QKV projection (bf16 A from prep), XCD-chunked, KV first ----------------
__global__ __launch_bounds__(512, 2) void proj_all(const u16* __restrict__ xb, const u16* __restrict__ cb,
                                                   const u16* __restrict__ wqT, const u16* __restrict__ wkvT,
                                                   u16* __restrict__ Qb, u16* __restrict__ Kb,
                                                   u16* __restrict__ Vtb, float qscale) {
  __shared__ alignas(16) u16 Ash[3 * 8192];    // 48 KB
  __shared__ alignas(16) u16 Bsh[3 * 16384];   // 96 KB
  int bx = blockIdx.x;
  if (bx < 128) {  // KV: M=4096, N=1024, K=768 -> 32x4 blocks of 128x256
    int bi = (bx & 7) * 16 + (bx >> 3);        // XCD-chunked [0,128)
    gemm8p<2>(cb, wkvT, Kb, Vtb, nullptr, 1024, 768, 1.0f, bi & 3, bi >> 2, Ash, Bsh);
  } else {         // Q: M=16384, N=512, K=512 -> 128x2 blocks
    int bq = bx - 128;
    int bi = (bq & 7) * 32 + (bq >> 3);        // [0,256)
    gemm8p<0>(xb, wqT, Qb, nullptr, nullptr, 512, 512, qscale, bi & 1, bi >> 1, Ash, Bsh);
  }
}

// ---------------- output projection (fp32 out + bias) ----------------
__global__ __launch_bounds__(512, 2) void outproj(const u16* __restrict__ Ob, const u16* __restrict__ woT,
                                                  float* __restrict__ out, const float* __restrict__ bo) {
  __shared__ alignas(16) u16 Ash[3 * 8192];
  __shared__ alignas(16) u16 Bsh[3 * 16384];
  int bx = blockIdx.x;
  int bi = (bx & 7) * 32 + (bx >> 3);          // [0,256)
  gemm8p<1>(Ob, woT, out, nullptr, bo, 512, 512, 1.0f, bi & 1, bi >> 1, Ash, Bsh);
}

// ---------------- flash cross-attention: 32 q/wave, 64-key tiles, 4 blocks/CU ----------------
// (unchanged from R1: MFMA-ones denominator, cvt_pk packs, pipelined chunks + setprio)
__global__ __launch_bounds__(256, 4) void attn(const u16* __restrict__ Q, const u16* __restrict__ Kb,
                                               const u16* __restrict__ Vt, u16* __restrict__ O) {
  __shared__ alignas(16) u16 Kl[2][64][64];   // 16 KB
  __shared__ alignas(16) u16 Vl[2][64][64];   // 16 KB
  int qt = blockIdx.x, h = blockIdx.y, b = blockIdx.z;
  int tid = threadIdx.x, wave = tid >> 6, lane = tid & 63, quad = lane >> 4, l16 = lane & 15;
  int q0 = qt * 128 + wave * 32;
  int x7 = l16 & 7;

  int kr = tid >> 3, kc = (tid & 7) ^ (kr & 7);
  const u16* kg = Kb + ((size_t)b * NC + kr) * 512 + h * DH + kc * 8;
  const u16* vg = Vt + ((size_t)(b * NH + h) * DH + kr) * NC + kc * 8;

#define ASTAGE(kt, buf) do { \
    const u16* kg_ = kg + (size_t)(kt) * 64 * 512; \
    const u16* vg_ = vg + (kt) * 64; \
    u16* kl_ = (u16*)Kl + (buf) * 4096; u16* vl_ = (u16*)Vl + (buf) * 4096; \
    g2l16(kg_,            kl_ + tid * 8); \
    g2l16(kg_ + 32 * 512, kl_ + (tid + 256) * 8); \
    g2l16(vg_,            vl_ + tid * 8); \
    g2l16(vg_ + 32 * NC,  vl_ + (tid + 256) * 8); } while (0)

  s8v aq[2][2];
  {
    const u16* Qp = Q + ((size_t)b * NQ + q0 + l16) * DI + h * DH + quad * 8;
    #pragma unroll
    for (int n = 0; n < 2; n++) {
      aq[n][0] = *(const s8v*)(Qp + (size_t)n * 16 * DI);
      aq[n][1] = *(const s8v*)(Qp + (size_t)n * 16 * DI + 32);
    }
  }
  s8v vones;
  #pragma unroll
  for (int i = 0; i < 8; i++) vones[i] = (short)0x3F80;

  f4v oacc[4][2];
  f4v lacc[2];
  #pragma unroll
  for (int d = 0; d < 4; d++)
    #pragma unroll
    for (int n = 0; n < 2; n++) oacc[d][n] = (f4v){0.f, 0.f, 0.f, 0.f};
  #pragma unroll
  for (int n = 0; n < 2; n++) lacc[n] = (f4v){0.f, 0.f, 0.f, 0.f};

  ASTAGE(0, 0);
  for (int kt = 0; kt < NC / 64; ++kt) {
    int buf = kt & 1;
    __syncthreads();
    if (kt + 1 < NC / 64) ASTAGE(kt + 1, buf ^ 1);
    const u16* kb = (const u16*)Kl + buf * 4096;
    const u16* vb = (const u16*)Vl + buf * 4096;

    f4v S0[2][2], S1[2][2];
    #pragma unroll
    for (int mi = 0; mi < 2; mi++)
      #pragma unroll
      for (int n = 0; n < 2; n++) { S0[mi][n] = (f4v){0.f,0.f,0.f,0.f}; S1[mi][n] = (f4v){0.f,0.f,0.f,0.f}; }
    __builtin_amdgcn_s_setprio(1);
    #pragma unroll
    for (int cd = 0; cd < 2; cd++) {
      int ch = ((4 * cd + quad) ^ x7) * 8;
      s8v k00 = *(const s8v*)(kb + (l16     ) * 64 + ch);
      s8v k01 = *(const s8v*)(kb + (l16 + 16) * 64 + ch);
      #pragma unroll
      for (int n = 0; n < 2; n++) {
        S0[0][n] = __builtin_amdgcn_mfma_f32_16x16x32_bf16(k00, aq[n][cd], S0[0][n], 0, 0, 0);
        S0[1][n] = __builtin_amdgcn_mfma_f32_16x16x32_bf16(k01, aq[n][cd], S0[1][n], 0, 0, 0);
      }
      s8v k10 = *(const s8v*)(kb + (l16 + 32) * 64 + ch);
      s8v k11 = *(const s8v*)(kb + (l16 + 48) * 64 + ch);
      #pragma unroll
      for (int n = 0; n < 2; n++) {
        S1[0][n] = __builtin_amdgcn_mfma_f32_16x16x32_bf16(k10, aq[n][cd], S1[0][n], 0, 0, 0);
        S1[1][n] = __builtin_amdgcn_mfma_f32_16x16x32_bf16(k11, aq[n][cd], S1[1][n], 0, 0, 0);
      }
    }
    __builtin_amdgcn_s_setprio(0);

    s8v pf0[2];
    #pragma unroll
    for (int n = 0; n < 2; n++) {
      float p00 = EXP2(S0[0][n][0]), p01 = EXP2(S0[0][n][1]), p02 = EXP2(S0[0][n][2]), p03 = EXP2(S0[0][n][3]);
      float p10 = EXP2(S0[1][n][0]), p11 = EXP2(S0[1][n][1]), p12 = EXP2(S0[1][n][2]), p13 = EXP2(S0[1][n][3]);
      union { u32 d[4]; s8v v; } u;
      u.d[0] = cvtpk(p00, p01); u.d[1] = cvtpk(p02, p03);
      u.d[2] = cvtpk(p10, p11); u.d[3] = cvtpk(p12, p13);
      pf0[n] = u.v;
    }
    __builtin_amdgcn_s_setprio(1);
    #pragma unroll
    for (int n = 0; n < 2; n++)
      lacc[n] = __builtin_amdgcn_mfma_f32_16x16x32_bf16(vones, pf0[n], lacc[n], 0, 0, 0);
    #pragma unroll
    for (int d = 0; d < 4; d++) {
      int ch = (quad ^ x7) * 8;
      s8v vf = *(const s8v*)(vb + (d * 16 + l16) * 64 + ch);
      #pragma unroll
      for (int n = 0; n < 2; n++)
        oacc[d][n] = __builtin_amdgcn_mfma_f32_16x16x32_bf16(vf, pf0[n], oacc[d][n], 0, 0, 0);
    }
    __builtin_amdgcn_s_setprio(0);

    s8v pf1[2];
    #pragma unroll
    for (int n = 0; n < 2; n++) {
      float p00 = EXP2(S1[0][n][0]), p01 = EXP2(S1[0][n][1]), p02 = EXP2(S1[0][n][2]), p03 = EXP2(S1[0][n][3]);
      float p10 = EXP2(S1[1][n][0]), p11 = EXP2(S1[1][n][1]), p12 = EXP2(S1[1][n][2]), p13 = EXP2(S1[1][n][3]);
      union { u32 d[4]; s8v v; } u;
      u.d[0] = cvtpk(p00, p01); u.d[1] = cvtpk(p02, p03);
      u.d[2] = cvtpk(p10, p11); u.d[3] = cvtpk(p12, p13);
      pf1[n] = u.v;
    }
    __builtin_amdgcn_s_setprio(1);
    #pragma unroll
    for (int n = 0; n < 2; n++)
      lacc[n] = __builtin_amdgcn_mfma_f32_16x16x32_bf16(vones, pf1[n], lacc[n], 0, 0, 0);
    #pragma unroll
    for (int d = 0; d < 4; d++) {
      int ch = ((4 + quad) ^ x7) * 8;
      s8v vf = *(const s8v*)(vb + (d * 16 + l16) * 64 + ch);
      #pragma unroll
      for (int n = 0; n < 2; n++)
        oacc[d][n] = __builtin_amdgcn_mfma_f32_16x16x32_bf16(vf, pf1[n], oacc[d][n], 0, 0, 0);
    }
    __builtin_amdgcn_s_setprio(0);
  }
#undef ASTAGE

  float inv[2];
  #pragma unroll
  for (int n = 0; n < 2; n++) inv[n] = 1.0f / lacc[n][0];

  #pragma unroll
  for (int d = 0; d < 4; d++)
    #pragma unroll
    for (int n = 0; n < 2; n++) {
      int q = q0 + n * 16 + l16;
      uint2 ov;
      ov.x = cvtpk(oacc[d][n][0] * inv[n], oacc[d][n][1] * inv[n]);
      ov.y = cvtpk(oacc[d][n][2] * inv[n], oacc[d][n][3] * inv[n]);
      *(uint2*)(O + ((size_t)b * NQ + q) * DI + h * DH + d * 16 + quad * 4) = ov;
    }
}

extern "C" void kernel_launch(void* const* d_in, const int* in_sizes, int n_in,
                              void* d_out, int out_size, void* d_ws, size_t ws_size,
                              hipStream_t stream) {
  const float* x   = (const float*)d_in[0];
  const float* ctx = (const float*)d_in[1];
  const float* Wq  = (const float*)d_in[2];
  const float* Wk  = (const float*)d_in[3];
  const float* Wv  = (const float*)d_in[4];
  const float* Wo  = (const float*)d_in[5];
  const float* bo  = (const float*)d_in[6];
  float* out = (float*)d_out;

  u16* w    = (u16*)d_ws;                // workspace layout (bf16 elems)
  u16* xb   = w;                         // 8388608
  u16* cb   = xb   + 8388608;            // 3145728
  u16* wqT  = cb   + 3145728;            // 262144
  u16* wkvT = wqT  + 262144;             // 786432 (Wk^T rows 0-511, Wv^T rows 512-1023)
  u16* woT  = wkvT + 786432;             // 262144
  u16* Qb   = woT  + 262144;             // 8388608 (pre-scaled by 0.125*log2e)
  u16* Kbuf = Qb   + 8388608;            // 2097152 ([b*1024+t][512])
  u16* Vtb  = Kbuf + 2097152;            // 2097152 (key-permuted V^T)
  u16* Ob   = Vtb  + 2097152;            // 8388608

  const float qscale = 0.125f * 1.44269504f;  // softmax scale + log2(e) folded into Q

  prep<<<11648, 256, 0, stream>>>(x, ctx, Wq, Wk, Wv, Wo, xb, cb, wqT, wkvT, woT);
  proj_all<<<384, 512, 0, stream>>>(xb, cb, wqT, wkvT, Qb, Kbuf, Vtb, qscale);
  attn<<<dim3(32, 8, 4), 256, 0, stream>>>(Qb, Kbuf, Vtb, Ob);
  outproj<<<256, 512, 0, stream>>>(Ob, woT, out, bo);
}